// Round 9
// baseline (1196.401 us; speedup 1.0000x reference)
//
#include <hip/hip_runtime.h>
#include <stdint.h>

#define N_NODES 50000
#define N_EDGES 800000
#define EMB 128
#define NPAD 50176        // padded to multiple of 128 rows for MLP (392 blocks x 128)
#define BN_EPS 1e-5f
#define SENT_KEY ((N_NODES << 5) | 21)   // sentinel: zero h-row, zero e12 entry
#define NODES_PER_XCD 6250               // 50000 / 8
#define XCHUNK 2048
#define NCHUNKS ((N_EDGES + XCHUNK - 1) / XCHUNK)   // 391

typedef __attribute__((ext_vector_type(8))) short short8;
typedef __attribute__((ext_vector_type(4))) float f32x4;

__device__ __forceinline__ float bf2f(unsigned short u) {
    return __uint_as_float(((unsigned int)u) << 16);
}
__device__ __forceinline__ unsigned short f2bf(float f) {
    unsigned int u = __float_as_uint(f);
    u += 0x7fffu + ((u >> 16) & 1u);   // RNE; values finite
    return (unsigned short)(u >> 16);
}
__device__ __forceinline__ float bflo(unsigned int v) { return __uint_as_float(v << 16); }
__device__ __forceinline__ float bfhi(unsigned int v) { return __uint_as_float(v & 0xffff0000u); }
__device__ __forceinline__ unsigned int packbf(float lo, float hi) {
    return (unsigned int)f2bf(lo) | ((unsigned int)f2bf(hi) << 16);
}

// ---------------- fused prep: embedding + zero(deg,cs,chist) + weight transpose/cast ----------
__global__ void k_prep(const int* __restrict__ x, const float* __restrict__ xe1,
                       const float* __restrict__ xe2, unsigned int* __restrict__ h,
                       const float* __restrict__ W1, const float* __restrict__ W2,
                       unsigned short* __restrict__ w1t, unsigned short* __restrict__ w2t,
                       int* __restrict__ deg, float* __restrict__ cs, int* __restrict__ chist) {
    int idx = blockIdx.x * 256 + threadIdx.x;   // [0, (N+1)*64)
    int i = idx >> 6, j = idx & 63;
    if (i < N_NODES) {
        int a = x[2 * i], c = x[2 * i + 1];
        float2 va = *(const float2*)(xe1 + a * EMB + j * 2);
        float2 vb = *(const float2*)(xe2 + c * EMB + j * 2);
        h[i * 64 + j] = packbf(va.x + vb.x, va.y + vb.y);
    } else if (i == N_NODES) {
        h[(size_t)i * 64 + j] = 0u;             // zero sentinel row
    }
    if (idx < 4 * 32768) {                      // weight transpose+cast
        int sec = idx >> 15, q = idx & 32767;
        if (sec < 2) {       // W1[sec]: [128][256] -> w1t[sec][c*128+r]
            int r = q >> 8, c = q & 255;
            w1t[sec * 32768 + c * 128 + r] = f2bf(W1[sec * 32768 + q]);
        } else {             // W2[sec-2]: [256][128] -> w2t[sec-2][c*256+r]
            int s = sec - 2;
            int r = q >> 7, c = q & 127;
            w2t[s * 32768 + c * 256 + r] = f2bf(W2[s * 32768 + q]);
        }
    }
    if (idx < N_NODES) deg[idx] = 0;
    if (idx < 512) cs[idx] = 0.f;
    if (idx < 16) chist[idx] = 0;
}

// ---------------- coalesced key precompute: keyv[e] = (src<<5) | (a0*3+a1) ----------------
__global__ void k_keys(const int* __restrict__ ei, const int* __restrict__ ea,
                       int* __restrict__ keyv) {
    int e = blockIdx.x * 256 + threadIdx.x;
    if (e >= N_EDGES) return;
    int2 aa = *(const int2*)(ea + 2 * e);
    keyv[e] = (ei[e] << 5) | (aa.x * 3 + aa.y);
}

// ---------------- CSR build (padded-to-16 per node), XCD-partitioned -------------
__global__ void k_hist(const int* __restrict__ dst, int* __restrict__ deg) {
    int xcd = blockIdx.x & 7, chunk = blockIdx.x >> 3;
    int lo = xcd * NODES_PER_XCD, hi = lo + NODES_PER_XCD;
    int e0 = chunk * XCHUNK + threadIdx.x * 4;
#pragma unroll
    for (int it = 0; it < XCHUNK / 1024; ++it) {
        int e = e0 + it * 1024;
        if (e < N_EDGES) {
            int4 d4 = *(const int4*)(dst + e);
            if (d4.x >= lo && d4.x < hi) atomicAdd(&deg[d4.x], 1);
            if (d4.y >= lo && d4.y < hi) atomicAdd(&deg[d4.y], 1);
            if (d4.z >= lo && d4.z < hi) atomicAdd(&deg[d4.z], 1);
            if (d4.w >= lo && d4.w < hi) atomicAdd(&deg[d4.w], 1);
        }
    }
}

// scan over PADDED degrees (pdeg=ceil(deg/16)*16) — shfl-based, 2 barriers
__global__ void k_scan1(const int* __restrict__ deg, int* __restrict__ part, int* __restrict__ bsums) {
    __shared__ int wsum[16];
    int lane = threadIdx.x & 63, wid = threadIdx.x >> 6;
    int i = blockIdx.x * 1024 + threadIdx.x;
    int d = (i < N_NODES) ? deg[i] : 0;
    int v = (d + 15) & ~15;
    int s = v;
#pragma unroll
    for (int off = 1; off < 64; off <<= 1) {
        int t = __shfl_up(s, off);
        if (lane >= off) s += t;
    }
    if (lane == 63) wsum[wid] = s;
    __syncthreads();
    if (wid == 0) {
        int w = (lane < 16) ? wsum[lane] : 0;
#pragma unroll
        for (int off = 1; off < 16; off <<= 1) {
            int t = __shfl_up(w, off);
            if (lane >= off) w += t;
        }
        if (lane < 16) wsum[lane] = w;   // inclusive wave-sum scan
    }
    __syncthreads();
    int base = (wid > 0) ? wsum[wid - 1] : 0;
    if (i < N_NODES) part[i] = base + s - v;   // exclusive within block
    if (threadIdx.x == 1023) bsums[blockIdx.x] = wsum[15];
}

// one-wave shuffle prefix scan over <=64 block sums
__global__ void k_scan2(int* __restrict__ bsums, int nb) {
    int lane = threadIdx.x;
    int v = (lane < nb) ? bsums[lane] : 0;
    int orig = v;
    for (int off = 1; off < 64; off <<= 1) {
        int t = __shfl_up(v, off);
        if (lane >= off) v += t;
    }
    if (lane < nb) bsums[lane] = v - orig;   // exclusive
}

// scan finalize + sentinel padding + chunk-count histogram (for degree bucketing)
__global__ void k_scan3(const int* __restrict__ part, const int* __restrict__ bsums,
                        const int* __restrict__ deg, int* __restrict__ offs,
                        int* __restrict__ cursor, int* __restrict__ keys,
                        int* __restrict__ chist) {
    int i = blockIdx.x * 256 + threadIdx.x;
    if (i >= N_NODES) return;
    int o = part[i] + bsums[i >> 10];
    offs[i] = o;
    cursor[i] = o;
    int d = deg[i], pd = (d + 15) & ~15;
    for (int j = d; j < pd; ++j) keys[o + j] = SENT_KEY;
    int nch = pd >> 4; if (nch > 15) nch = 15;
    atomicAdd(&chist[nch], 1);
    if (i == N_NODES - 1) offs[N_NODES] = o + pd;
}

// tiny: exclusive scan of 16-bin chist -> bin cursors
__global__ void k_scanB(const int* __restrict__ chist, int* __restrict__ cursor2) {
    int lane = threadIdx.x;
    int v = (lane < 16) ? chist[lane] : 0;
    int s = v;
#pragma unroll
    for (int off = 1; off < 16; off <<= 1) {
        int t = __shfl_up(s, off);
        if (lane >= off) s += t;
    }
    if (lane < 16) cursor2[lane] = s - v;   // exclusive base
}

// scatter nodes into degree buckets: perm[slot] = node
__global__ void k_perm(const int* __restrict__ offs, int* __restrict__ cursor2,
                       int* __restrict__ perm) {
    int i = blockIdx.x * 256 + threadIdx.x;
    if (i >= N_NODES) return;
    int nch = (offs[i + 1] - offs[i]) >> 4; if (nch > 15) nch = 15;
    int slot = atomicAdd(&cursor2[nch], 1);
    perm[slot] = i;
}

// fill packed keys via keyv gather, XCD-partitioned, int4 dst loads
__global__ void k_fill(const int* __restrict__ dst, const int* __restrict__ keyv,
                       int* __restrict__ cursor, int* __restrict__ keys) {
    int xcd = blockIdx.x & 7, chunk = blockIdx.x >> 3;
    int lo = xcd * NODES_PER_XCD, hi = lo + NODES_PER_XCD;
    int e0 = chunk * XCHUNK + threadIdx.x * 4;
#pragma unroll
    for (int it = 0; it < XCHUNK / 1024; ++it) {
        int e = e0 + it * 1024;
        if (e < N_EDGES) {
            int4 d4 = *(const int4*)(dst + e);
            int dv[4] = {d4.x, d4.y, d4.z, d4.w};
#pragma unroll
            for (int q = 0; q < 4; ++q) {
                int d = dv[q];
                if (d >= lo && d < hi) {
                    int p = atomicAdd(&cursor[d], 1);
                    keys[p] = keyv[e + q];
                }
            }
        }
    }
}

// ---------------- aggregation v5: degree-bucketed, one node per 16-lane group ---------------
// perm groups equal-chunk-count nodes into the same wave -> no wasted sentinel
// iterations from the wave-level maxch. One dwordx4 serves 4 edges; 16-trip
// unrolled j-loop keeps 16 independent gathers in flight at low VGPR.
__global__ __launch_bounds__(256) void k_agg(
    const unsigned int* __restrict__ h,        // [(N+1)][64] packed bf16x2 (row N = zeros)
    const int* __restrict__ offs,              // [N+1] padded offsets
    const int* __restrict__ keys,              // padded packed keys
    const int* __restrict__ perm,              // degree-bucketed node order
    const float* __restrict__ e1l, const float* __restrict__ e2l,
    unsigned int* __restrict__ agg)            // [NPAD][64] packed bf16x2
{
    __shared__ float e12[22 * 132];            // stride 132 staggers rows across banks
    for (int t = threadIdx.x; t < 22 * 128; t += 256) {
        int combo = t >> 7, f = t & 127;
        float v = 0.f;
        if (combo < 21) {
            int a0 = combo / 3, a1 = combo - a0 * 3;
            v = e1l[a0 * EMB + f] + e2l[a1 * EMB + f];
        }
        e12[combo * 132 + f] = v;
    }
    __syncthreads();
    int wave = threadIdx.x >> 6, lane = threadIdx.x & 63;
    int sub = lane >> 4, fl = lane & 15;
    int idx = blockIdx.x * 16 + wave * 4 + sub;
    int node = idx;                            // pad rows [N, NPAD): write zeros
    float ax[8] = {0.f, 0.f, 0.f, 0.f, 0.f, 0.f, 0.f, 0.f};
    int o = 0, nch = 0;
    if (idx < N_NODES) {
        node = perm[idx];
        o = offs[node];
        nch = (offs[node + 1] - o) >> 4;
        // self loop: attr=[4,0] -> combo 12
        uint4 hv = *(const uint4*)(h + (size_t)node * 64 + fl * 4);
        const float* ep = e12 + 12 * 132 + fl * 8;
        float4 e0 = *(const float4*)ep, e1_ = *(const float4*)(ep + 4);
        ax[0] = bflo(hv.x) + e0.x;  ax[1] = bfhi(hv.x) + e0.y;
        ax[2] = bflo(hv.y) + e0.z;  ax[3] = bfhi(hv.y) + e0.w;
        ax[4] = bflo(hv.z) + e1_.x; ax[5] = bfhi(hv.z) + e1_.y;
        ax[6] = bflo(hv.w) + e1_.z; ax[7] = bfhi(hv.w) + e1_.w;
    }
    int maxch = nch;
#pragma unroll
    for (int d = 32; d; d >>= 1) maxch = max(maxch, __shfl_xor(maxch, d));
    int key = (0 < nch) ? keys[o + fl] : SENT_KEY;
    for (int c = 0; c < maxch; ++c) {
        int keyn = (c + 1 < nch) ? keys[o + (c + 1) * 16 + fl] : SENT_KEY;
#pragma unroll
        for (int j = 0; j < 16; ++j) {
            int kj = __shfl(key, sub * 16 + j);
            uint4 g = *(const uint4*)(h + (size_t)(kj >> 5) * 64 + fl * 4);
            const float* ep = e12 + (kj & 31) * 132 + fl * 8;
            float4 e0 = *(const float4*)ep, e1_ = *(const float4*)(ep + 4);
            ax[0] += bflo(g.x) + e0.x;  ax[1] += bfhi(g.x) + e0.y;
            ax[2] += bflo(g.y) + e0.z;  ax[3] += bfhi(g.y) + e0.w;
            ax[4] += bflo(g.z) + e1_.x; ax[5] += bfhi(g.z) + e1_.y;
            ax[6] += bflo(g.w) + e1_.z; ax[7] += bfhi(g.w) + e1_.w;
        }
        key = keyn;
    }
    uint4 out;
    out.x = packbf(ax[0], ax[1]); out.y = packbf(ax[2], ax[3]);
    out.z = packbf(ax[4], ax[5]); out.w = packbf(ax[6], ax[7]);
    *(uint4*)(agg + (size_t)node * 64 + fl * 4) = out;   // pad rows -> zeros
}

// ---------------- fused MLP v2: h2 = relu(agg@W1+b1)@W2+b2, no LDS ----------------
// GEMM1 operand-swapped (A=w1 frag, B=agg frag) -> D is t-transposed in C-layout;
// 8 shuffles + 4 selects convert to GEMM2's A-fragment. M=32 rows/wave register
// blocking. h2 aliases agg: waves are row-disjoint.
__global__ __launch_bounds__(256, 2) void k_mlp(
    unsigned short* aggh2,                     // [NPAD][128] bf16 in, [N][128] bf16 out
    const unsigned short* __restrict__ w1t,    // [256][128]  (W1 transposed: [n][k])
    const float* __restrict__ b1,              // [256]
    const unsigned short* __restrict__ w2t,    // [128][256]  (W2 transposed: [n][k])
    const float* __restrict__ b2)              // [128]
{
    int lane = threadIdx.x & 63;
    int wave = threadIdx.x >> 6;
    int quad = lane >> 4, r16 = lane & 15;
    int m0 = (blockIdx.x * 4 + wave) * 32;     // 32 rows per wave
    int sel  = (lane >> 5) & 1;                // which nt tile my A2 comes from
    int srcA = ((lane >> 4) & 1) * 32 + r16;   // source lane for j=0..3
    int srcB = srcA + 16;                      // source lane for j=4..7

    // agg B-frags (GEMM1 swapped): B[k=quad*8+j][node=r16]
    short8 bagg[2][4];
#pragma unroll
    for (int t = 0; t < 2; ++t)
#pragma unroll
        for (int c = 0; c < 4; ++c)
            bagg[t][c] = *(const short8*)(aggh2 + (size_t)(m0 + t * 16 + r16) * 128 + c * 32 + quad * 8);

    float b2v[8];
#pragma unroll
    for (int n = 0; n < 8; ++n) b2v[n] = b2[n * 16 + r16];

    f32x4 acc2[2][8];
#pragma unroll
    for (int t = 0; t < 2; ++t)
#pragma unroll
        for (int n = 0; n < 8; ++n) acc2[t][n] = (f32x4){0.f, 0.f, 0.f, 0.f};

    for (int c2 = 0; c2 < 8; ++c2) {
        unsigned int pk[2][2][2];              // [ntl][tile][dword]
#pragma unroll
        for (int ntl = 0; ntl < 2; ++ntl) {
            int nt = c2 * 2 + ntl;
            short8 aw[4];
#pragma unroll
            for (int c = 0; c < 4; ++c)
                aw[c] = *(const short8*)(w1t + (nt * 16 + r16) * 128 + c * 32 + quad * 8);
            float4 bv = *(const float4*)(b1 + nt * 16 + quad * 4);
#pragma unroll
            for (int t = 0; t < 2; ++t) {
                f32x4 a1 = {0.f, 0.f, 0.f, 0.f};
#pragma unroll
                for (int c = 0; c < 4; ++c)
                    a1 = __builtin_amdgcn_mfma_f32_16x16x32_bf16(aw[c], bagg[t][c], a1, 0, 0, 0);
                float v0 = a1[0] + bv.x; v0 = v0 > 0.f ? v0 : 0.f;
                float v1 = a1[1] + bv.y; v1 = v1 > 0.f ? v1 : 0.f;
                float v2 = a1[2] + bv.z; v2 = v2 > 0.f ? v2 : 0.f;
                float v3 = a1[3] + bv.w; v3 = v3 > 0.f ? v3 : 0.f;
                pk[ntl][t][0] = packbf(v0, v1);
                pk[ntl][t][1] = packbf(v2, v3);
            }
        }
        short8 a2f[2];
#pragma unroll
        for (int t = 0; t < 2; ++t) {
            int u0 = __shfl((int)pk[0][t][0], srcA), w0 = __shfl((int)pk[1][t][0], srcA);
            int u1 = __shfl((int)pk[0][t][1], srcA), w1_ = __shfl((int)pk[1][t][1], srcA);
            int u2 = __shfl((int)pk[0][t][0], srcB), w2_ = __shfl((int)pk[1][t][0], srcB);
            int u3 = __shfl((int)pk[0][t][1], srcB), w3_ = __shfl((int)pk[1][t][1], srcB);
            union { int i[4]; short8 s; } a2u;
            a2u.i[0] = sel ? w0 : u0;
            a2u.i[1] = sel ? w1_ : u1;
            a2u.i[2] = sel ? w2_ : u2;
            a2u.i[3] = sel ? w3_ : u3;
            a2f[t] = a2u.s;
        }
#pragma unroll
        for (int n = 0; n < 8; ++n) {
            short8 bw = *(const short8*)(w2t + (n * 16 + r16) * 256 + c2 * 32 + quad * 8);
            acc2[0][n] = __builtin_amdgcn_mfma_f32_16x16x32_bf16(a2f[0], bw, acc2[0][n], 0, 0, 0);
            acc2[1][n] = __builtin_amdgcn_mfma_f32_16x16x32_bf16(a2f[1], bw, acc2[1][n], 0, 0, 0);
        }
    }
#pragma unroll
    for (int t = 0; t < 2; ++t)
#pragma unroll
        for (int n = 0; n < 8; ++n)
#pragma unroll
            for (int r = 0; r < 4; ++r) {
                int row = m0 + t * 16 + quad * 4 + r;
                if (row < N_NODES)
                    aggh2[(size_t)row * 128 + n * 16 + r16] = f2bf(acc2[t][n][r] + b2v[n]);
            }
}

// ---------------- BN stats: per-column sum & sumsq (fp32), LDS-reduced, 250 blocks ----------------
__global__ void k_bnstats(const unsigned int* __restrict__ h2, float* __restrict__ cs) {
    __shared__ float4 sm[256];
    int p = threadIdx.x & 63;                  // column pair
    int g = threadIdx.x >> 6;                  // 0..3
    int r0 = blockIdx.x * 200;                 // 250 blocks x 200 rows = 50000
    float s0 = 0.f, s1 = 0.f, q0 = 0.f, q1 = 0.f;
    for (int r = r0 + g; r < r0 + 200; r += 4) {
        unsigned int v = h2[(size_t)r * 64 + p];
        float a = bflo(v), b = bfhi(v);
        s0 += a; q0 += a * a;
        s1 += b; q1 += b * b;
    }
    sm[threadIdx.x] = make_float4(s0, s1, q0, q1);
    __syncthreads();
    if (threadIdx.x < 64) {
        float4 a = sm[p], b = sm[p + 64], c = sm[p + 128], d = sm[p + 192];
        atomicAdd(&cs[2 * p],       a.x + b.x + c.x + d.x);
        atomicAdd(&cs[2 * p + 1],   a.y + b.y + c.y + d.y);
        atomicAdd(&cs[128 + 2 * p],     a.z + b.z + c.z + d.z);
        atomicAdd(&cs[128 + 2 * p + 1], a.w + b.w + c.w + d.w);
    }
}

// ---------------- BN normalize (+relu for layer 0 -> bf16 h; layer 1 -> fp32 d_out) ----------------
__global__ void k_bnnorm(const unsigned int* __restrict__ h2, const float* __restrict__ cs,
                         const float* __restrict__ gamma, const float* __restrict__ beta,
                         unsigned int* __restrict__ outb, float2* __restrict__ outf, int mode) {
    int idx = blockIdx.x * 256 + threadIdx.x;  // [0, N*64)
    if (idx >= N_NODES * 64) return;
    int p = idx & 63;
    int c0 = 2 * p, c1 = 2 * p + 1;
    float m0 = cs[c0] * (1.f / N_NODES);
    float m1 = cs[c1] * (1.f / N_NODES);
    float v0 = cs[128 + c0] * (1.f / N_NODES) - m0 * m0;
    float v1 = cs[128 + c1] * (1.f / N_NODES) - m1 * m1;
    float r0 = rsqrtf(v0 + BN_EPS), r1 = rsqrtf(v1 + BN_EPS);
    unsigned int hv = h2[idx];
    float a = (bflo(hv) - m0) * r0 * gamma[c0] + beta[c0];
    float b = (bfhi(hv) - m1) * r1 * gamma[c1] + beta[c1];
    if (mode == 0) {
        a = a > 0.f ? a : 0.f;
        b = b > 0.f ? b : 0.f;
        outb[idx] = packbf(a, b);
    } else {
        outf[idx] = make_float2(a, b);
    }
}

extern "C" void kernel_launch(void* const* d_in, const int* in_sizes, int n_in,
                              void* d_out, int out_size, void* d_ws, size_t ws_size,
                              hipStream_t stream) {
    const int* x  = (const int*)d_in[0];
    const int* ei = (const int*)d_in[1];
    const int* ea = (const int*)d_in[2];
    // d_in[3] = batch (unused)
    const float* xe1 = (const float*)d_in[4];
    const float* xe2 = (const float*)d_in[5];
    const float* e1  = (const float*)d_in[6];   // [2][7][128]
    const float* e2  = (const float*)d_in[7];   // [2][3][128]
    const float* W1  = (const float*)d_in[8];   // [2][128][256]
    const float* b1  = (const float*)d_in[9];   // [2][256]
    const float* W2  = (const float*)d_in[10];  // [2][256][128]
    const float* b2  = (const float*)d_in[11];  // [2][128]
    const float* gm  = (const float*)d_in[12];  // [2][128]
    const float* bt  = (const float*)d_in[13];  // [2][128]

    char* ws = (char*)d_ws;
    size_t off = 0;
    auto take = [&](size_t bytes) -> char* {
        char* p = ws + off;
        off = (off + bytes + 255) & ~(size_t)255;
        return p;
    };
    unsigned int* h_buf = (unsigned int*)take((size_t)(N_NODES + 1) * 64 * 4); // +1 zero row
    unsigned int* aggb  = (unsigned int*)take((size_t)NPAD * 64 * 4);          // agg, then h2
    unsigned short* w1t = (unsigned short*)take((size_t)2 * 32768 * 2);
    unsigned short* w2t = (unsigned short*)take((size_t)2 * 32768 * 2);
    int* deg    = (int*)take((size_t)N_NODES * 4);
    int* offs   = (int*)take((size_t)(N_NODES + 1) * 4);
    int* cursor = (int*)take((size_t)N_NODES * 4);
    int* keys   = (int*)take((size_t)(N_EDGES + N_NODES * 16) * 4);
    int* keyv   = (int*)take((size_t)N_EDGES * 4);
    int* perm   = (int*)take((size_t)N_NODES * 4);
    int* bsums  = (int*)take(64 * 4);
    int* chist  = (int*)take(16 * 4);
    int* cursor2= (int*)take(16 * 4);
    float* cs   = (float*)take(512 * 4);

    k_prep<<<((N_NODES + 1) * 64 + 255) / 256, 256, 0, stream>>>(x, xe1, xe2, h_buf,
                                                                 W1, W2, w1t, w2t, deg, cs, chist);
    k_keys<<<(N_EDGES + 255) / 256, 256, 0, stream>>>(ei, ea, keyv);
    k_hist<<<8 * NCHUNKS, 256, 0, stream>>>(ei + N_EDGES, deg);
    k_scan1<<<49, 1024, 0, stream>>>(deg, offs, bsums);   // offs used as 'part' scratch here
    k_scan2<<<1, 64, 0, stream>>>(bsums, 49);
    k_scan3<<<(N_NODES + 255) / 256, 256, 0, stream>>>(offs, bsums, deg, offs, cursor, keys, chist);
    k_scanB<<<1, 64, 0, stream>>>(chist, cursor2);
    k_perm<<<(N_NODES + 255) / 256, 256, 0, stream>>>(offs, cursor2, perm);
    k_fill<<<8 * NCHUNKS, 256, 0, stream>>>(ei + N_EDGES, keyv, cursor, keys);

    for (int l = 0; l < 2; ++l) {
        k_agg<<<NPAD / 16, 256, 0, stream>>>(h_buf, offs, keys, perm,
                                             e1 + l * 896, e2 + l * 384, aggb);
        k_mlp<<<NPAD / 128, 256, 0, stream>>>((unsigned short*)aggb, w1t + l * 32768, b1 + l * 256,
                                              w2t + l * 32768, b2 + l * 128);
        k_bnstats<<<250, 256, 0, stream>>>(aggb, cs + l * 256);
        k_bnnorm<<<(N_NODES * 64) / 256, 256, 0, stream>>>(aggb, cs + l * 256, gm + l * 128, bt + l * 128,
                                                           h_buf, (float2*)d_out, l);
    }
}

// Round 10
// 411.708 us; speedup vs baseline: 2.9059x; 2.9059x over previous
//
#include <hip/hip_runtime.h>
#include <stdint.h>

#define N_NODES 50000
#define N_EDGES 800000
#define EMB 128
#define NPAD 50176        // padded to multiple of 128 rows for MLP (392 blocks x 128)
#define BN_EPS 1e-5f
#define SENT_KEY ((N_NODES << 5) | 21)   // sentinel: zero h-row, zero e12 entry
#define NODES_PER_XCD 6250               // 50000 / 8
#define XCHUNK 2048
#define NCHUNKS ((N_EDGES + XCHUNK - 1) / XCHUNK)   // 391
#define NBLK 196                         // ceil(50000/256) blocks for bucket hist/perm

typedef __attribute__((ext_vector_type(8))) short short8;
typedef __attribute__((ext_vector_type(4))) float f32x4;

__device__ __forceinline__ float bf2f(unsigned short u) {
    return __uint_as_float(((unsigned int)u) << 16);
}
__device__ __forceinline__ unsigned short f2bf(float f) {
    unsigned int u = __float_as_uint(f);
    u += 0x7fffu + ((u >> 16) & 1u);   // RNE; values finite
    return (unsigned short)(u >> 16);
}
__device__ __forceinline__ float bflo(unsigned int v) { return __uint_as_float(v << 16); }
__device__ __forceinline__ float bfhi(unsigned int v) { return __uint_as_float(v & 0xffff0000u); }
__device__ __forceinline__ unsigned int packbf(float lo, float hi) {
    return (unsigned int)f2bf(lo) | ((unsigned int)f2bf(hi) << 16);
}

// ---------------- fused prep: embedding + zero(deg,cs) + weight transpose/cast ----------------
__global__ void k_prep(const int* __restrict__ x, const float* __restrict__ xe1,
                       const float* __restrict__ xe2, unsigned int* __restrict__ h,
                       const float* __restrict__ W1, const float* __restrict__ W2,
                       unsigned short* __restrict__ w1t, unsigned short* __restrict__ w2t,
                       int* __restrict__ deg, float* __restrict__ cs) {
    int idx = blockIdx.x * 256 + threadIdx.x;   // [0, (N+1)*64)
    int i = idx >> 6, j = idx & 63;
    if (i < N_NODES) {
        int a = x[2 * i], c = x[2 * i + 1];
        float2 va = *(const float2*)(xe1 + a * EMB + j * 2);
        float2 vb = *(const float2*)(xe2 + c * EMB + j * 2);
        h[i * 64 + j] = packbf(va.x + vb.x, va.y + vb.y);
    } else if (i == N_NODES) {
        h[(size_t)i * 64 + j] = 0u;             // zero sentinel row
    }
    if (idx < 4 * 32768) {                      // weight transpose+cast
        int sec = idx >> 15, q = idx & 32767;
        if (sec < 2) {       // W1[sec]: [128][256] -> w1t[sec][c*128+r]
            int r = q >> 8, c = q & 255;
            w1t[sec * 32768 + c * 128 + r] = f2bf(W1[sec * 32768 + q]);
        } else {             // W2[sec-2]: [256][128] -> w2t[sec-2][c*256+r]
            int s = sec - 2;
            int r = q >> 7, c = q & 127;
            w2t[s * 32768 + c * 256 + r] = f2bf(W2[s * 32768 + q]);
        }
    }
    if (idx < N_NODES) deg[idx] = 0;
    if (idx < 512) cs[idx] = 0.f;
}

// ---------------- coalesced key precompute: keyv[e] = (src<<5) | (a0*3+a1) ----------------
__global__ void k_keys(const int* __restrict__ ei, const int* __restrict__ ea,
                       int* __restrict__ keyv) {
    int e = blockIdx.x * 256 + threadIdx.x;
    if (e >= N_EDGES) return;
    int2 aa = *(const int2*)(ea + 2 * e);
    keyv[e] = (ei[e] << 5) | (aa.x * 3 + aa.y);
}

// ---------------- CSR build (padded-to-16 per node), XCD-partitioned -------------
__global__ void k_hist(const int* __restrict__ dst, int* __restrict__ deg) {
    int xcd = blockIdx.x & 7, chunk = blockIdx.x >> 3;
    int lo = xcd * NODES_PER_XCD, hi = lo + NODES_PER_XCD;
    int e0 = chunk * XCHUNK + threadIdx.x * 4;
#pragma unroll
    for (int it = 0; it < XCHUNK / 1024; ++it) {
        int e = e0 + it * 1024;
        if (e < N_EDGES) {
            int4 d4 = *(const int4*)(dst + e);
            if (d4.x >= lo && d4.x < hi) atomicAdd(&deg[d4.x], 1);
            if (d4.y >= lo && d4.y < hi) atomicAdd(&deg[d4.y], 1);
            if (d4.z >= lo && d4.z < hi) atomicAdd(&deg[d4.z], 1);
            if (d4.w >= lo && d4.w < hi) atomicAdd(&deg[d4.w], 1);
        }
    }
}

// scan over PADDED degrees (pdeg=ceil(deg/16)*16) — shfl-based, 2 barriers
__global__ void k_scan1(const int* __restrict__ deg, int* __restrict__ part, int* __restrict__ bsums) {
    __shared__ int wsum[16];
    int lane = threadIdx.x & 63, wid = threadIdx.x >> 6;
    int i = blockIdx.x * 1024 + threadIdx.x;
    int d = (i < N_NODES) ? deg[i] : 0;
    int v = (d + 15) & ~15;
    int s = v;
#pragma unroll
    for (int off = 1; off < 64; off <<= 1) {
        int t = __shfl_up(s, off);
        if (lane >= off) s += t;
    }
    if (lane == 63) wsum[wid] = s;
    __syncthreads();
    if (wid == 0) {
        int w = (lane < 16) ? wsum[lane] : 0;
#pragma unroll
        for (int off = 1; off < 16; off <<= 1) {
            int t = __shfl_up(w, off);
            if (lane >= off) w += t;
        }
        if (lane < 16) wsum[lane] = w;   // inclusive wave-sum scan
    }
    __syncthreads();
    int base = (wid > 0) ? wsum[wid - 1] : 0;
    if (i < N_NODES) part[i] = base + s - v;   // exclusive within block
    if (threadIdx.x == 1023) bsums[blockIdx.x] = wsum[15];
}

// one-wave shuffle prefix scan over <=64 block sums
__global__ void k_scan2(int* __restrict__ bsums, int nb) {
    int lane = threadIdx.x;
    int v = (lane < nb) ? bsums[lane] : 0;
    int orig = v;
    for (int off = 1; off < 64; off <<= 1) {
        int t = __shfl_up(v, off);
        if (lane >= off) v += t;
    }
    if (lane < nb) bsums[lane] = v - orig;   // exclusive
}

// scan finalize + sentinel padding fused (round-8 form; NO shared-line atomics)
__global__ void k_scan3(const int* __restrict__ part, const int* __restrict__ bsums,
                        const int* __restrict__ deg, int* __restrict__ offs,
                        int* __restrict__ cursor, int* __restrict__ keys) {
    int i = blockIdx.x * 256 + threadIdx.x;
    if (i >= N_NODES) return;
    int o = part[i] + bsums[i >> 10];
    offs[i] = o;
    cursor[i] = o;
    int d = deg[i], pd = (d + 15) & ~15;
    for (int j = d; j < pd; ++j) keys[o + j] = SENT_KEY;
    if (i == N_NODES - 1) offs[N_NODES] = o + pd;
}

// per-block LDS histogram of chunk counts -> bh[bin][blk]  (bin-major)
__global__ void k_hist2(const int* __restrict__ offs, int* __restrict__ bh) {
    __shared__ int lh[16];
    if (threadIdx.x < 16) lh[threadIdx.x] = 0;
    __syncthreads();
    int i = blockIdx.x * 256 + threadIdx.x;
    if (i < N_NODES) {
        int nch = (offs[i + 1] - offs[i]) >> 4; if (nch > 15) nch = 15;
        atomicAdd(&lh[nch], 1);      // LDS atomic: intra-CU, fast
    }
    __syncthreads();
    if (threadIdx.x < 16) bh[threadIdx.x * NBLK + blockIdx.x] = lh[threadIdx.x];
}

// single-block exclusive scan over bh (16*NBLK = 3136 entries, bin-major)
__global__ void k_scanC(int* __restrict__ bh) {
    __shared__ int ws[16];
    int tid = threadIdx.x;                 // 1024 threads x 4 elements
    int lane = tid & 63, wid = tid >> 6;
    int base = tid * 4;
    int v[4], s = 0;
#pragma unroll
    for (int k = 0; k < 4; ++k) {
        int idx = base + k;
        v[k] = (idx < 16 * NBLK) ? bh[idx] : 0;
        s += v[k];
    }
    int ssum = s;
#pragma unroll
    for (int off = 1; off < 64; off <<= 1) {
        int t = __shfl_up(ssum, off);
        if (lane >= off) ssum += t;
    }
    if (lane == 63) ws[wid] = ssum;
    __syncthreads();
    if (wid == 0) {
        int w = (lane < 16) ? ws[lane] : 0;
#pragma unroll
        for (int off = 1; off < 16; off <<= 1) {
            int t = __shfl_up(w, off);
            if (lane >= off) w += t;
        }
        if (lane < 16) ws[lane] = w;
    }
    __syncthreads();
    int tbase = ((wid > 0) ? ws[wid - 1] : 0) + ssum - s;   // exclusive base
#pragma unroll
    for (int k = 0; k < 4; ++k) {
        int idx = base + k;
        if (idx < 16 * NBLK) bh[idx] = tbase;
        tbase += v[k];
    }
}

// scatter nodes into degree buckets via per-block LDS ranks (3136 global atomics total: none)
__global__ void k_perm2(const int* __restrict__ offs, const int* __restrict__ bh,
                        int* __restrict__ perm) {
    __shared__ int lh[16];
    if (threadIdx.x < 16) lh[threadIdx.x] = 0;
    __syncthreads();
    int i = blockIdx.x * 256 + threadIdx.x;
    if (i < N_NODES) {
        int nch = (offs[i + 1] - offs[i]) >> 4; if (nch > 15) nch = 15;
        int r = atomicAdd(&lh[nch], 1);        // LDS atomic rank
        perm[bh[nch * NBLK + blockIdx.x] + r] = i;
    }
}

// fill packed keys via keyv gather, XCD-partitioned, int4 dst loads
__global__ void k_fill(const int* __restrict__ dst, const int* __restrict__ keyv,
                       int* __restrict__ cursor, int* __restrict__ keys) {
    int xcd = blockIdx.x & 7, chunk = blockIdx.x >> 3;
    int lo = xcd * NODES_PER_XCD, hi = lo + NODES_PER_XCD;
    int e0 = chunk * XCHUNK + threadIdx.x * 4;
#pragma unroll
    for (int it = 0; it < XCHUNK / 1024; ++it) {
        int e = e0 + it * 1024;
        if (e < N_EDGES) {
            int4 d4 = *(const int4*)(dst + e);
            int dv[4] = {d4.x, d4.y, d4.z, d4.w};
#pragma unroll
            for (int q = 0; q < 4; ++q) {
                int d = dv[q];
                if (d >= lo && d < hi) {
                    int p = atomicAdd(&cursor[d], 1);
                    keys[p] = keyv[e + q];
                }
            }
        }
    }
}

// ---------------- aggregation v5: degree-bucketed, one node per 16-lane group ---------------
// perm groups equal-chunk-count nodes into the same wave -> no wasted sentinel
// iterations from the wave-level maxch. One dwordx4 serves 4 edges; 16-trip
// unrolled j-loop keeps 16 independent gathers in flight at low VGPR.
__global__ __launch_bounds__(256) void k_agg(
    const unsigned int* __restrict__ h,        // [(N+1)][64] packed bf16x2 (row N = zeros)
    const int* __restrict__ offs,              // [N+1] padded offsets
    const int* __restrict__ keys,              // padded packed keys
    const int* __restrict__ perm,              // degree-bucketed node order
    const float* __restrict__ e1l, const float* __restrict__ e2l,
    unsigned int* __restrict__ agg)            // [NPAD][64] packed bf16x2
{
    __shared__ float e12[22 * 132];            // stride 132 staggers rows across banks
    for (int t = threadIdx.x; t < 22 * 128; t += 256) {
        int combo = t >> 7, f = t & 127;
        float v = 0.f;
        if (combo < 21) {
            int a0 = combo / 3, a1 = combo - a0 * 3;
            v = e1l[a0 * EMB + f] + e2l[a1 * EMB + f];
        }
        e12[combo * 132 + f] = v;
    }
    __syncthreads();
    int wave = threadIdx.x >> 6, lane = threadIdx.x & 63;
    int sub = lane >> 4, fl = lane & 15;
    int idx = blockIdx.x * 16 + wave * 4 + sub;
    int node = idx;                            // pad rows [N, NPAD): write zeros
    float ax[8] = {0.f, 0.f, 0.f, 0.f, 0.f, 0.f, 0.f, 0.f};
    int o = 0, nch = 0;
    if (idx < N_NODES) {
        node = perm[idx];
        o = offs[node];
        nch = (offs[node + 1] - o) >> 4;
        // self loop: attr=[4,0] -> combo 12
        uint4 hv = *(const uint4*)(h + (size_t)node * 64 + fl * 4);
        const float* ep = e12 + 12 * 132 + fl * 8;
        float4 e0 = *(const float4*)ep, e1_ = *(const float4*)(ep + 4);
        ax[0] = bflo(hv.x) + e0.x;  ax[1] = bfhi(hv.x) + e0.y;
        ax[2] = bflo(hv.y) + e0.z;  ax[3] = bfhi(hv.y) + e0.w;
        ax[4] = bflo(hv.z) + e1_.x; ax[5] = bfhi(hv.z) + e1_.y;
        ax[6] = bflo(hv.w) + e1_.z; ax[7] = bfhi(hv.w) + e1_.w;
    }
    int maxch = nch;
#pragma unroll
    for (int d = 32; d; d >>= 1) maxch = max(maxch, __shfl_xor(maxch, d));
    int key = (0 < nch) ? keys[o + fl] : SENT_KEY;
    for (int c = 0; c < maxch; ++c) {
        int keyn = (c + 1 < nch) ? keys[o + (c + 1) * 16 + fl] : SENT_KEY;
#pragma unroll
        for (int j = 0; j < 16; ++j) {
            int kj = __shfl(key, sub * 16 + j);
            uint4 g = *(const uint4*)(h + (size_t)(kj >> 5) * 64 + fl * 4);
            const float* ep = e12 + (kj & 31) * 132 + fl * 8;
            float4 e0 = *(const float4*)ep, e1_ = *(const float4*)(ep + 4);
            ax[0] += bflo(g.x) + e0.x;  ax[1] += bfhi(g.x) + e0.y;
            ax[2] += bflo(g.y) + e0.z;  ax[3] += bfhi(g.y) + e0.w;
            ax[4] += bflo(g.z) + e1_.x; ax[5] += bfhi(g.z) + e1_.y;
            ax[6] += bflo(g.w) + e1_.z; ax[7] += bfhi(g.w) + e1_.w;
        }
        key = keyn;
    }
    uint4 out;
    out.x = packbf(ax[0], ax[1]); out.y = packbf(ax[2], ax[3]);
    out.z = packbf(ax[4], ax[5]); out.w = packbf(ax[6], ax[7]);
    *(uint4*)(agg + (size_t)node * 64 + fl * 4) = out;   // pad rows -> zeros
}

// ---------------- fused MLP v2: h2 = relu(agg@W1+b1)@W2+b2, no LDS ----------------
// GEMM1 operand-swapped (A=w1 frag, B=agg frag) -> D is t-transposed in C-layout;
// 8 shuffles + 4 selects convert to GEMM2's A-fragment. M=32 rows/wave register
// blocking. h2 aliases agg: waves are row-disjoint.
__global__ __launch_bounds__(256, 2) void k_mlp(
    unsigned short* aggh2,                     // [NPAD][128] bf16 in, [N][128] bf16 out
    const unsigned short* __restrict__ w1t,    // [256][128]  (W1 transposed: [n][k])
    const float* __restrict__ b1,              // [256]
    const unsigned short* __restrict__ w2t,    // [128][256]  (W2 transposed: [n][k])
    const float* __restrict__ b2)              // [128]
{
    int lane = threadIdx.x & 63;
    int wave = threadIdx.x >> 6;
    int quad = lane >> 4, r16 = lane & 15;
    int m0 = (blockIdx.x * 4 + wave) * 32;     // 32 rows per wave
    int sel  = (lane >> 5) & 1;                // which nt tile my A2 comes from
    int srcA = ((lane >> 4) & 1) * 32 + r16;   // source lane for j=0..3
    int srcB = srcA + 16;                      // source lane for j=4..7

    // agg B-frags (GEMM1 swapped): B[k=quad*8+j][node=r16]
    short8 bagg[2][4];
#pragma unroll
    for (int t = 0; t < 2; ++t)
#pragma unroll
        for (int c = 0; c < 4; ++c)
            bagg[t][c] = *(const short8*)(aggh2 + (size_t)(m0 + t * 16 + r16) * 128 + c * 32 + quad * 8);

    float b2v[8];
#pragma unroll
    for (int n = 0; n < 8; ++n) b2v[n] = b2[n * 16 + r16];

    f32x4 acc2[2][8];
#pragma unroll
    for (int t = 0; t < 2; ++t)
#pragma unroll
        for (int n = 0; n < 8; ++n) acc2[t][n] = (f32x4){0.f, 0.f, 0.f, 0.f};

    for (int c2 = 0; c2 < 8; ++c2) {
        unsigned int pk[2][2][2];              // [ntl][tile][dword]
#pragma unroll
        for (int ntl = 0; ntl < 2; ++ntl) {
            int nt = c2 * 2 + ntl;
            short8 aw[4];
#pragma unroll
            for (int c = 0; c < 4; ++c)
                aw[c] = *(const short8*)(w1t + (nt * 16 + r16) * 128 + c * 32 + quad * 8);
            float4 bv = *(const float4*)(b1 + nt * 16 + quad * 4);
#pragma unroll
            for (int t = 0; t < 2; ++t) {
                f32x4 a1 = {0.f, 0.f, 0.f, 0.f};
#pragma unroll
                for (int c = 0; c < 4; ++c)
                    a1 = __builtin_amdgcn_mfma_f32_16x16x32_bf16(aw[c], bagg[t][c], a1, 0, 0, 0);
                float v0 = a1[0] + bv.x; v0 = v0 > 0.f ? v0 : 0.f;
                float v1 = a1[1] + bv.y; v1 = v1 > 0.f ? v1 : 0.f;
                float v2 = a1[2] + bv.z; v2 = v2 > 0.f ? v2 : 0.f;
                float v3 = a1[3] + bv.w; v3 = v3 > 0.f ? v3 : 0.f;
                pk[ntl][t][0] = packbf(v0, v1);
                pk[ntl][t][1] = packbf(v2, v3);
            }
        }
        short8 a2f[2];
#pragma unroll
        for (int t = 0; t < 2; ++t) {
            int u0 = __shfl((int)pk[0][t][0], srcA), w0 = __shfl((int)pk[1][t][0], srcA);
            int u1 = __shfl((int)pk[0][t][1], srcA), w1_ = __shfl((int)pk[1][t][1], srcA);
            int u2 = __shfl((int)pk[0][t][0], srcB), w2_ = __shfl((int)pk[1][t][0], srcB);
            int u3 = __shfl((int)pk[0][t][1], srcB), w3_ = __shfl((int)pk[1][t][1], srcB);
            union { int i[4]; short8 s; } a2u;
            a2u.i[0] = sel ? w0 : u0;
            a2u.i[1] = sel ? w1_ : u1;
            a2u.i[2] = sel ? w2_ : u2;
            a2u.i[3] = sel ? w3_ : u3;
            a2f[t] = a2u.s;
        }
#pragma unroll
        for (int n = 0; n < 8; ++n) {
            short8 bw = *(const short8*)(w2t + (n * 16 + r16) * 256 + c2 * 32 + quad * 8);
            acc2[0][n] = __builtin_amdgcn_mfma_f32_16x16x32_bf16(a2f[0], bw, acc2[0][n], 0, 0, 0);
            acc2[1][n] = __builtin_amdgcn_mfma_f32_16x16x32_bf16(a2f[1], bw, acc2[1][n], 0, 0, 0);
        }
    }
#pragma unroll
    for (int t = 0; t < 2; ++t)
#pragma unroll
        for (int n = 0; n < 8; ++n)
#pragma unroll
            for (int r = 0; r < 4; ++r) {
                int row = m0 + t * 16 + quad * 4 + r;
                if (row < N_NODES)
                    aggh2[(size_t)row * 128 + n * 16 + r16] = f2bf(acc2[t][n][r] + b2v[n]);
            }
}

// ---------------- BN stats: per-column sum & sumsq (fp32), LDS-reduced, 250 blocks ----------------
__global__ void k_bnstats(const unsigned int* __restrict__ h2, float* __restrict__ cs) {
    __shared__ float4 sm[256];
    int p = threadIdx.x & 63;                  // column pair
    int g = threadIdx.x >> 6;                  // 0..3
    int r0 = blockIdx.x * 200;                 // 250 blocks x 200 rows = 50000
    float s0 = 0.f, s1 = 0.f, q0 = 0.f, q1 = 0.f;
    for (int r = r0 + g; r < r0 + 200; r += 4) {
        unsigned int v = h2[(size_t)r * 64 + p];
        float a = bflo(v), b = bfhi(v);
        s0 += a; q0 += a * a;
        s1 += b; q1 += b * b;
    }
    sm[threadIdx.x] = make_float4(s0, s1, q0, q1);
    __syncthreads();
    if (threadIdx.x < 64) {
        float4 a = sm[p], b = sm[p + 64], c = sm[p + 128], d = sm[p + 192];
        atomicAdd(&cs[2 * p],       a.x + b.x + c.x + d.x);
        atomicAdd(&cs[2 * p + 1],   a.y + b.y + c.y + d.y);
        atomicAdd(&cs[128 + 2 * p],     a.z + b.z + c.z + d.z);
        atomicAdd(&cs[128 + 2 * p + 1], a.w + b.w + c.w + d.w);
    }
}

// ---------------- BN normalize (+relu for layer 0 -> bf16 h; layer 1 -> fp32 d_out) ----------------
__global__ void k_bnnorm(const unsigned int* __restrict__ h2, const float* __restrict__ cs,
                         const float* __restrict__ gamma, const float* __restrict__ beta,
                         unsigned int* __restrict__ outb, float2* __restrict__ outf, int mode) {
    int idx = blockIdx.x * 256 + threadIdx.x;  // [0, N*64)
    if (idx >= N_NODES * 64) return;
    int p = idx & 63;
    int c0 = 2 * p, c1 = 2 * p + 1;
    float m0 = cs[c0] * (1.f / N_NODES);
    float m1 = cs[c1] * (1.f / N_NODES);
    float v0 = cs[128 + c0] * (1.f / N_NODES) - m0 * m0;
    float v1 = cs[128 + c1] * (1.f / N_NODES) - m1 * m1;
    float r0 = rsqrtf(v0 + BN_EPS), r1 = rsqrtf(v1 + BN_EPS);
    unsigned int hv = h2[idx];
    float a = (bflo(hv) - m0) * r0 * gamma[c0] + beta[c0];
    float b = (bfhi(hv) - m1) * r1 * gamma[c1] + beta[c1];
    if (mode == 0) {
        a = a > 0.f ? a : 0.f;
        b = b > 0.f ? b : 0.f;
        outb[idx] = packbf(a, b);
    } else {
        outf[idx] = make_float2(a, b);
    }
}

extern "C" void kernel_launch(void* const* d_in, const int* in_sizes, int n_in,
                              void* d_out, int out_size, void* d_ws, size_t ws_size,
                              hipStream_t stream) {
    const int* x  = (const int*)d_in[0];
    const int* ei = (const int*)d_in[1];
    const int* ea = (const int*)d_in[2];
    // d_in[3] = batch (unused)
    const float* xe1 = (const float*)d_in[4];
    const float* xe2 = (const float*)d_in[5];
    const float* e1  = (const float*)d_in[6];   // [2][7][128]
    const float* e2  = (const float*)d_in[7];   // [2][3][128]
    const float* W1  = (const float*)d_in[8];   // [2][128][256]
    const float* b1  = (const float*)d_in[9];   // [2][256]
    const float* W2  = (const float*)d_in[10];  // [2][256][128]
    const float* b2  = (const float*)d_in[11];  // [2][128]
    const float* gm  = (const float*)d_in[12];  // [2][128]
    const float* bt  = (const float*)d_in[13];  // [2][128]

    char* ws = (char*)d_ws;
    size_t off = 0;
    auto take = [&](size_t bytes) -> char* {
        char* p = ws + off;
        off = (off + bytes + 255) & ~(size_t)255;
        return p;
    };
    unsigned int* h_buf = (unsigned int*)take((size_t)(N_NODES + 1) * 64 * 4); // +1 zero row
    unsigned int* aggb  = (unsigned int*)take((size_t)NPAD * 64 * 4);          // agg, then h2
    unsigned short* w1t = (unsigned short*)take((size_t)2 * 32768 * 2);
    unsigned short* w2t = (unsigned short*)take((size_t)2 * 32768 * 2);
    int* deg    = (int*)take((size_t)N_NODES * 4);
    int* offs   = (int*)take((size_t)(N_NODES + 1) * 4);
    int* cursor = (int*)take((size_t)N_NODES * 4);
    int* keys   = (int*)take((size_t)(N_EDGES + N_NODES * 16) * 4);
    int* keyv   = (int*)take((size_t)N_EDGES * 4);
    int* perm   = (int*)take((size_t)N_NODES * 4);
    int* bsums  = (int*)take(64 * 4);
    int* bh     = (int*)take((size_t)16 * NBLK * 4);
    float* cs   = (float*)take(512 * 4);

    k_prep<<<((N_NODES + 1) * 64 + 255) / 256, 256, 0, stream>>>(x, xe1, xe2, h_buf,
                                                                 W1, W2, w1t, w2t, deg, cs);
    k_keys<<<(N_EDGES + 255) / 256, 256, 0, stream>>>(ei, ea, keyv);
    k_hist<<<8 * NCHUNKS, 256, 0, stream>>>(ei + N_EDGES, deg);
    k_scan1<<<49, 1024, 0, stream>>>(deg, offs, bsums);   // offs used as 'part' scratch here
    k_scan2<<<1, 64, 0, stream>>>(bsums, 49);
    k_scan3<<<(N_NODES + 255) / 256, 256, 0, stream>>>(offs, bsums, deg, offs, cursor, keys);
    k_hist2<<<NBLK, 256, 0, stream>>>(offs, bh);
    k_scanC<<<1, 1024, 0, stream>>>(bh);
    k_perm2<<<NBLK, 256, 0, stream>>>(offs, bh, perm);
    k_fill<<<8 * NCHUNKS, 256, 0, stream>>>(ei + N_EDGES, keyv, cursor, keys);

    for (int l = 0; l < 2; ++l) {
        k_agg<<<NPAD / 16, 256, 0, stream>>>(h_buf, offs, keys, perm,
                                             e1 + l * 896, e2 + l * 384, aggb);
        k_mlp<<<NPAD / 128, 256, 0, stream>>>((unsigned short*)aggb, w1t + l * 32768, b1 + l * 256,
                                              w2t + l * 32768, b2 + l * 128);
        k_bnstats<<<250, 256, 0, stream>>>(aggb, cs + l * 256);
        k_bnnorm<<<(N_NODES * 64) / 256, 256, 0, stream>>>(aggb, cs + l * 256, gm + l * 128, bt + l * 128,
                                                           h_buf, (float2*)d_out, l);
    }
}

// Round 11
// 391.422 us; speedup vs baseline: 3.0565x; 1.0518x over previous
//
#include <hip/hip_runtime.h>
#include <stdint.h>

#define N_NODES 50000
#define N_EDGES 800000
#define EMB 128
#define NPAD 50176        // padded to multiple of 128 rows for MLP (392 blocks x 128)
#define MBLK 392          // NPAD / 128
#define BN_EPS 1e-5f
#define SENT_KEY ((N_NODES << 5) | 21)   // sentinel: zero h-row, zero e12 entry
#define NODES_PER_XCD 6250               // 50000 / 8
#define XCHUNK 2048
#define NCHUNKS ((N_EDGES + XCHUNK - 1) / XCHUNK)   // 391

typedef __attribute__((ext_vector_type(8))) short short8;
typedef __attribute__((ext_vector_type(4))) float f32x4;

__device__ __forceinline__ float bf2f(unsigned short u) {
    return __uint_as_float(((unsigned int)u) << 16);
}
__device__ __forceinline__ unsigned short f2bf(float f) {
    unsigned int u = __float_as_uint(f);
    u += 0x7fffu + ((u >> 16) & 1u);   // RNE; values finite
    return (unsigned short)(u >> 16);
}
__device__ __forceinline__ float bflo(unsigned int v) { return __uint_as_float(v << 16); }
__device__ __forceinline__ float bfhi(unsigned int v) { return __uint_as_float(v & 0xffff0000u); }
__device__ __forceinline__ unsigned int packbf(float lo, float hi) {
    return (unsigned int)f2bf(lo) | ((unsigned int)f2bf(hi) << 16);
}

// ------- fused prep: embedding + zero(deg) + weight transpose/cast + key precompute -------
__global__ void k_prep(const int* __restrict__ x, const float* __restrict__ xe1,
                       const float* __restrict__ xe2, unsigned int* __restrict__ h,
                       const float* __restrict__ W1, const float* __restrict__ W2,
                       unsigned short* __restrict__ w1t, unsigned short* __restrict__ w2t,
                       int* __restrict__ deg,
                       const int* __restrict__ ei, const int* __restrict__ ea,
                       int* __restrict__ keyv) {
    int idx = blockIdx.x * 256 + threadIdx.x;   // [0, (N+1)*64)
    int i = idx >> 6, j = idx & 63;
    if (i < N_NODES) {
        int a = x[2 * i], c = x[2 * i + 1];
        float2 va = *(const float2*)(xe1 + a * EMB + j * 2);
        float2 vb = *(const float2*)(xe2 + c * EMB + j * 2);
        h[i * 64 + j] = packbf(va.x + vb.x, va.y + vb.y);
    } else if (i == N_NODES) {
        h[(size_t)i * 64 + j] = 0u;             // zero sentinel row
    }
    if (idx < 4 * 32768) {                      // weight transpose+cast
        int sec = idx >> 15, q = idx & 32767;
        if (sec < 2) {       // W1[sec]: [128][256] -> w1t[sec][c*128+r]
            int r = q >> 8, c = q & 255;
            w1t[sec * 32768 + c * 128 + r] = f2bf(W1[sec * 32768 + q]);
        } else {             // W2[sec-2]: [256][128] -> w2t[sec-2][c*256+r]
            int s = sec - 2;
            int r = q >> 7, c = q & 127;
            w2t[s * 32768 + c * 256 + r] = f2bf(W2[s * 32768 + q]);
        }
    }
    if (idx < N_EDGES) {                        // packed key precompute
        int2 aa = *(const int2*)(ea + 2 * idx);
        keyv[idx] = (ei[idx] << 5) | (aa.x * 3 + aa.y);
    }
    if (idx < N_NODES) deg[idx] = 0;
}

// ---------------- CSR build (padded-to-16 per node), XCD-partitioned -------------
__global__ void k_hist(const int* __restrict__ dst, int* __restrict__ deg) {
    int xcd = blockIdx.x & 7, chunk = blockIdx.x >> 3;
    int lo = xcd * NODES_PER_XCD, hi = lo + NODES_PER_XCD;
    int e0 = chunk * XCHUNK + threadIdx.x * 4;
#pragma unroll
    for (int it = 0; it < XCHUNK / 1024; ++it) {
        int e = e0 + it * 1024;
        if (e < N_EDGES) {
            int4 d4 = *(const int4*)(dst + e);
            if (d4.x >= lo && d4.x < hi) atomicAdd(&deg[d4.x], 1);
            if (d4.y >= lo && d4.y < hi) atomicAdd(&deg[d4.y], 1);
            if (d4.z >= lo && d4.z < hi) atomicAdd(&deg[d4.z], 1);
            if (d4.w >= lo && d4.w < hi) atomicAdd(&deg[d4.w], 1);
        }
    }
}

// scan over PADDED degrees (pdeg=ceil(deg/16)*16) — shfl-based, 2 barriers
__global__ void k_scan1(const int* __restrict__ deg, int* __restrict__ part, int* __restrict__ bsums) {
    __shared__ int wsum[16];
    int lane = threadIdx.x & 63, wid = threadIdx.x >> 6;
    int i = blockIdx.x * 1024 + threadIdx.x;
    int d = (i < N_NODES) ? deg[i] : 0;
    int v = (d + 15) & ~15;
    int s = v;
#pragma unroll
    for (int off = 1; off < 64; off <<= 1) {
        int t = __shfl_up(s, off);
        if (lane >= off) s += t;
    }
    if (lane == 63) wsum[wid] = s;
    __syncthreads();
    if (wid == 0) {
        int w = (lane < 16) ? wsum[lane] : 0;
#pragma unroll
        for (int off = 1; off < 16; off <<= 1) {
            int t = __shfl_up(w, off);
            if (lane >= off) w += t;
        }
        if (lane < 16) wsum[lane] = w;   // inclusive wave-sum scan
    }
    __syncthreads();
    int base = (wid > 0) ? wsum[wid - 1] : 0;
    if (i < N_NODES) part[i] = base + s - v;   // exclusive within block
    if (threadIdx.x == 1023) bsums[blockIdx.x] = wsum[15];
}

// one-wave shuffle prefix scan over <=64 block sums
__global__ void k_scan2(int* __restrict__ bsums, int nb) {
    int lane = threadIdx.x;
    int v = (lane < nb) ? bsums[lane] : 0;
    int orig = v;
    for (int off = 1; off < 64; off <<= 1) {
        int t = __shfl_up(v, off);
        if (lane >= off) v += t;
    }
    if (lane < nb) bsums[lane] = v - orig;   // exclusive
}

// scan finalize + sentinel padding fused
__global__ void k_scan3(const int* __restrict__ part, const int* __restrict__ bsums,
                        const int* __restrict__ deg, int* __restrict__ offs,
                        int* __restrict__ cursor, int* __restrict__ keys) {
    int i = blockIdx.x * 256 + threadIdx.x;
    if (i >= N_NODES) return;
    int o = part[i] + bsums[i >> 10];
    offs[i] = o;
    cursor[i] = o;
    int d = deg[i], pd = (d + 15) & ~15;
    for (int j = d; j < pd; ++j) keys[o + j] = SENT_KEY;
    if (i == N_NODES - 1) offs[N_NODES] = o + pd;
}

// fill packed keys via keyv gather, XCD-partitioned, int4 dst loads
__global__ void k_fill(const int* __restrict__ dst, const int* __restrict__ keyv,
                       int* __restrict__ cursor, int* __restrict__ keys) {
    int xcd = blockIdx.x & 7, chunk = blockIdx.x >> 3;
    int lo = xcd * NODES_PER_XCD, hi = lo + NODES_PER_XCD;
    int e0 = chunk * XCHUNK + threadIdx.x * 4;
#pragma unroll
    for (int it = 0; it < XCHUNK / 1024; ++it) {
        int e = e0 + it * 1024;
        if (e < N_EDGES) {
            int4 d4 = *(const int4*)(dst + e);
            int dv[4] = {d4.x, d4.y, d4.z, d4.w};
#pragma unroll
            for (int q = 0; q < 4; ++q) {
                int d = dv[q];
                if (d >= lo && d < hi) {
                    int p = atomicAdd(&cursor[d], 1);
                    keys[p] = keyv[e + q];
                }
            }
        }
    }
}

// ---------------- aggregation (round-8 proven form): one node per 16-lane group -------------
// One global_load_dwordx4 serves 4 edges; 16-trip unrolled j-loop keeps 16
// independent gathers in flight at low VGPR -> high occupancy.
__global__ __launch_bounds__(256) void k_agg(
    const unsigned int* __restrict__ h,        // [(N+1)][64] packed bf16x2 (row N = zeros)
    const int* __restrict__ offs,              // [N+1] padded offsets
    const int* __restrict__ keys,              // padded packed keys
    const float* __restrict__ e1l, const float* __restrict__ e2l,
    unsigned int* __restrict__ agg)            // [NPAD][64] packed bf16x2
{
    __shared__ float e12[22 * 132];            // stride 132 staggers rows across banks
    for (int t = threadIdx.x; t < 22 * 128; t += 256) {
        int combo = t >> 7, f = t & 127;
        float v = 0.f;
        if (combo < 21) {
            int a0 = combo / 3, a1 = combo - a0 * 3;
            v = e1l[a0 * EMB + f] + e2l[a1 * EMB + f];
        }
        e12[combo * 132 + f] = v;
    }
    __syncthreads();
    int wave = threadIdx.x >> 6, lane = threadIdx.x & 63;
    int sub = lane >> 4, fl = lane & 15;
    int node = blockIdx.x * 16 + wave * 4 + sub;
    float ax[8] = {0.f, 0.f, 0.f, 0.f, 0.f, 0.f, 0.f, 0.f};
    int o = 0, nch = 0;
    if (node < N_NODES) {
        o = offs[node];
        nch = (offs[node + 1] - o) >> 4;
        // self loop: attr=[4,0] -> combo 12
        uint4 hv = *(const uint4*)(h + (size_t)node * 64 + fl * 4);
        const float* ep = e12 + 12 * 132 + fl * 8;
        float4 e0 = *(const float4*)ep, e1_ = *(const float4*)(ep + 4);
        ax[0] = bflo(hv.x) + e0.x;  ax[1] = bfhi(hv.x) + e0.y;
        ax[2] = bflo(hv.y) + e0.z;  ax[3] = bfhi(hv.y) + e0.w;
        ax[4] = bflo(hv.z) + e1_.x; ax[5] = bfhi(hv.z) + e1_.y;
        ax[6] = bflo(hv.w) + e1_.z; ax[7] = bfhi(hv.w) + e1_.w;
    }
    int maxch = nch;
#pragma unroll
    for (int d = 32; d; d >>= 1) maxch = max(maxch, __shfl_xor(maxch, d));
    int key = (0 < nch) ? keys[o + fl] : SENT_KEY;
    for (int c = 0; c < maxch; ++c) {
        int keyn = (c + 1 < nch) ? keys[o + (c + 1) * 16 + fl] : SENT_KEY;
#pragma unroll
        for (int j = 0; j < 16; ++j) {
            int kj = __shfl(key, sub * 16 + j);
            uint4 g = *(const uint4*)(h + (size_t)(kj >> 5) * 64 + fl * 4);
            const float* ep = e12 + (kj & 31) * 132 + fl * 8;
            float4 e0 = *(const float4*)ep, e1_ = *(const float4*)(ep + 4);
            ax[0] += bflo(g.x) + e0.x;  ax[1] += bfhi(g.x) + e0.y;
            ax[2] += bflo(g.y) + e0.z;  ax[3] += bfhi(g.y) + e0.w;
            ax[4] += bflo(g.z) + e1_.x; ax[5] += bfhi(g.z) + e1_.y;
            ax[6] += bflo(g.w) + e1_.z; ax[7] += bfhi(g.w) + e1_.w;
        }
        key = keyn;
    }
    if (node < NPAD) {
        uint4 out;
        out.x = packbf(ax[0], ax[1]); out.y = packbf(ax[2], ax[3]);
        out.z = packbf(ax[4], ax[5]); out.w = packbf(ax[6], ax[7]);
        *(uint4*)(agg + (size_t)node * 64 + fl * 4) = out;   // pad rows -> zeros
    }
}

// ---------------- fused MLP + BN partial stats: h2 = relu(agg@W1+b1)@W2+b2 ----------------
// GEMM1 operand-swapped -> D is t-transposed in C-layout; 8 shuffles + 4 selects
// convert to GEMM2's A-fragment. M=32 rows/wave register blocking. h2 aliases agg.
// NEW: per-block BN column sums/sumsq from the fp32 accumulators -> partials[blk][256]
// (plain stores, no global atomics — round-9 lesson).
__global__ __launch_bounds__(256, 2) void k_mlp(
    unsigned short* aggh2,                     // [NPAD][128] bf16 in, [N][128] bf16 out
    const unsigned short* __restrict__ w1t,    // [256][128]  (W1 transposed: [n][k])
    const float* __restrict__ b1,              // [256]
    const unsigned short* __restrict__ w2t,    // [128][256]  (W2 transposed: [n][k])
    const float* __restrict__ b2,              // [128]
    float* __restrict__ partials)              // [MBLK][256]: cols 0..127 sum, 128..255 sumsq
{
    __shared__ float bn[256];
    int lane = threadIdx.x & 63;
    int wave = threadIdx.x >> 6;
    int quad = lane >> 4, r16 = lane & 15;
    int m0 = (blockIdx.x * 4 + wave) * 32;     // 32 rows per wave
    int sel  = (lane >> 5) & 1;
    int srcA = ((lane >> 4) & 1) * 32 + r16;
    int srcB = srcA + 16;
    bn[threadIdx.x] = 0.f;

    // agg B-frags (GEMM1 swapped): B[k=quad*8+j][node=r16]
    short8 bagg[2][4];
#pragma unroll
    for (int t = 0; t < 2; ++t)
#pragma unroll
        for (int c = 0; c < 4; ++c)
            bagg[t][c] = *(const short8*)(aggh2 + (size_t)(m0 + t * 16 + r16) * 128 + c * 32 + quad * 8);

    float b2v[8];
#pragma unroll
    for (int n = 0; n < 8; ++n) b2v[n] = b2[n * 16 + r16];

    f32x4 acc2[2][8];
#pragma unroll
    for (int t = 0; t < 2; ++t)
#pragma unroll
        for (int n = 0; n < 8; ++n) acc2[t][n] = (f32x4){0.f, 0.f, 0.f, 0.f};

    for (int c2 = 0; c2 < 8; ++c2) {
        unsigned int pk[2][2][2];              // [ntl][tile][dword]
#pragma unroll
        for (int ntl = 0; ntl < 2; ++ntl) {
            int nt = c2 * 2 + ntl;
            short8 aw[4];
#pragma unroll
            for (int c = 0; c < 4; ++c)
                aw[c] = *(const short8*)(w1t + (nt * 16 + r16) * 128 + c * 32 + quad * 8);
            float4 bv = *(const float4*)(b1 + nt * 16 + quad * 4);
#pragma unroll
            for (int t = 0; t < 2; ++t) {
                f32x4 a1 = {0.f, 0.f, 0.f, 0.f};
#pragma unroll
                for (int c = 0; c < 4; ++c)
                    a1 = __builtin_amdgcn_mfma_f32_16x16x32_bf16(aw[c], bagg[t][c], a1, 0, 0, 0);
                float v0 = a1[0] + bv.x; v0 = v0 > 0.f ? v0 : 0.f;
                float v1 = a1[1] + bv.y; v1 = v1 > 0.f ? v1 : 0.f;
                float v2 = a1[2] + bv.z; v2 = v2 > 0.f ? v2 : 0.f;
                float v3 = a1[3] + bv.w; v3 = v3 > 0.f ? v3 : 0.f;
                pk[ntl][t][0] = packbf(v0, v1);
                pk[ntl][t][1] = packbf(v2, v3);
            }
        }
        short8 a2f[2];
#pragma unroll
        for (int t = 0; t < 2; ++t) {
            int u0 = __shfl((int)pk[0][t][0], srcA), w0 = __shfl((int)pk[1][t][0], srcA);
            int u1 = __shfl((int)pk[0][t][1], srcA), w1_ = __shfl((int)pk[1][t][1], srcA);
            int u2 = __shfl((int)pk[0][t][0], srcB), w2_ = __shfl((int)pk[1][t][0], srcB);
            int u3 = __shfl((int)pk[0][t][1], srcB), w3_ = __shfl((int)pk[1][t][1], srcB);
            union { int i[4]; short8 s; } a2u;
            a2u.i[0] = sel ? w0 : u0;
            a2u.i[1] = sel ? w1_ : u1;
            a2u.i[2] = sel ? w2_ : u2;
            a2u.i[3] = sel ? w3_ : u3;
            a2f[t] = a2u.s;
        }
#pragma unroll
        for (int n = 0; n < 8; ++n) {
            short8 bw = *(const short8*)(w2t + (n * 16 + r16) * 256 + c2 * 32 + quad * 8);
            acc2[0][n] = __builtin_amdgcn_mfma_f32_16x16x32_bf16(a2f[0], bw, acc2[0][n], 0, 0, 0);
            acc2[1][n] = __builtin_amdgcn_mfma_f32_16x16x32_bf16(a2f[1], bw, acc2[1][n], 0, 0, 0);
        }
    }
    // epilogue: store h2 + accumulate per-lane BN partial sums (fp32, rows < N only)
    float s[8], q[8];
#pragma unroll
    for (int n = 0; n < 8; ++n) { s[n] = 0.f; q[n] = 0.f; }
#pragma unroll
    for (int t = 0; t < 2; ++t)
#pragma unroll
        for (int n = 0; n < 8; ++n)
#pragma unroll
            for (int r = 0; r < 4; ++r) {
                int row = m0 + t * 16 + quad * 4 + r;
                float v = acc2[t][n][r] + b2v[n];
                if (row < N_NODES) {
                    aggh2[(size_t)row * 128 + n * 16 + r16] = f2bf(v);
                    s[n] += v; q[n] += v * v;
                }
            }
    // reduce over quads (same col set): lanes differ in bits 4,5
#pragma unroll
    for (int n = 0; n < 8; ++n) {
        s[n] += __shfl_xor(s[n], 16); q[n] += __shfl_xor(q[n], 16);
        s[n] += __shfl_xor(s[n], 32); q[n] += __shfl_xor(q[n], 32);
    }
    __syncthreads();          // bn[] zero-init visible
    if (quad == 0) {          // 16 lanes per wave x 4 waves -> LDS atomics
#pragma unroll
        for (int n = 0; n < 8; ++n) {
            atomicAdd(&bn[n * 16 + r16], s[n]);
            atomicAdd(&bn[128 + n * 16 + r16], q[n]);
        }
    }
    __syncthreads();
    partials[(size_t)blockIdx.x * 256 + threadIdx.x] = bn[threadIdx.x];
}

// ---------------- BN reduce: partials -> per-col scale/shift (1 block) ----------------
__global__ void k_bnred(const float* __restrict__ partials, const float* __restrict__ gamma,
                        const float* __restrict__ beta, float* __restrict__ ab) {
    __shared__ float tot[256];
    int tid = threadIdx.x;                 // 256 threads
    float sum = 0.f;
    for (int b = 0; b < MBLK; ++b) sum += partials[(size_t)b * 256 + tid];
    tot[tid] = sum;
    __syncthreads();
    if (tid < 128) {
        float mean = tot[tid] * (1.f / N_NODES);
        float var  = tot[128 + tid] * (1.f / N_NODES) - mean * mean;
        float rstd = rsqrtf(var + BN_EPS);
        float g = gamma[tid];
        ab[tid]       = g * rstd;                       // scale
        ab[128 + tid] = beta[tid] - mean * g * rstd;    // shift
    }
}

// ---------------- BN apply (+relu for layer 0 -> bf16 h; layer 1 -> fp32 d_out) ----------------
__global__ void k_bnnorm(const unsigned int* __restrict__ h2, const float* __restrict__ ab,
                         unsigned int* __restrict__ outb, float2* __restrict__ outf, int mode) {
    int idx = blockIdx.x * 256 + threadIdx.x;  // [0, N*64)
    if (idx >= N_NODES * 64) return;
    int p = idx & 63;
    int c0 = 2 * p, c1 = 2 * p + 1;
    float a0 = ab[c0], a1 = ab[c1], s0 = ab[128 + c0], s1 = ab[128 + c1];
    unsigned int hv = h2[idx];
    float a = bflo(hv) * a0 + s0;
    float b = bfhi(hv) * a1 + s1;
    if (mode == 0) {
        a = a > 0.f ? a : 0.f;
        b = b > 0.f ? b : 0.f;
        outb[idx] = packbf(a, b);
    } else {
        outf[idx] = make_float2(a, b);
    }
}

extern "C" void kernel_launch(void* const* d_in, const int* in_sizes, int n_in,
                              void* d_out, int out_size, void* d_ws, size_t ws_size,
                              hipStream_t stream) {
    const int* x  = (const int*)d_in[0];
    const int* ei = (const int*)d_in[1];
    const int* ea = (const int*)d_in[2];
    // d_in[3] = batch (unused)
    const float* xe1 = (const float*)d_in[4];
    const float* xe2 = (const float*)d_in[5];
    const float* e1  = (const float*)d_in[6];   // [2][7][128]
    const float* e2  = (const float*)d_in[7];   // [2][3][128]
    const float* W1  = (const float*)d_in[8];   // [2][128][256]
    const float* b1  = (const float*)d_in[9];   // [2][256]
    const float* W2  = (const float*)d_in[10];  // [2][256][128]
    const float* b2  = (const float*)d_in[11];  // [2][128]
    const float* gm  = (const float*)d_in[12];  // [2][128]
    const float* bt  = (const float*)d_in[13];  // [2][128]

    char* ws = (char*)d_ws;
    size_t off = 0;
    auto take = [&](size_t bytes) -> char* {
        char* p = ws + off;
        off = (off + bytes + 255) & ~(size_t)255;
        return p;
    };
    unsigned int* h_buf = (unsigned int*)take((size_t)(N_NODES + 1) * 64 * 4); // +1 zero row
    unsigned int* aggb  = (unsigned int*)take((size_t)NPAD * 64 * 4);          // agg, then h2
    unsigned short* w1t = (unsigned short*)take((size_t)2 * 32768 * 2);
    unsigned short* w2t = (unsigned short*)take((size_t)2 * 32768 * 2);
    int* deg    = (int*)take((size_t)N_NODES * 4);
    int* offs   = (int*)take((size_t)(N_NODES + 1) * 4);
    int* cursor = (int*)take((size_t)N_NODES * 4);
    int* keys   = (int*)take((size_t)(N_EDGES + N_NODES * 16) * 4);
    int* keyv   = (int*)take((size_t)N_EDGES * 4);
    int* bsums  = (int*)take(64 * 4);
    float* partials = (float*)take((size_t)MBLK * 256 * 4);
    float* ab   = (float*)take(256 * 4);

    k_prep<<<((N_NODES + 1) * 64 + 255) / 256, 256, 0, stream>>>(x, xe1, xe2, h_buf,
                                                                 W1, W2, w1t, w2t, deg,
                                                                 ei, ea, keyv);
    k_hist<<<8 * NCHUNKS, 256, 0, stream>>>(ei + N_EDGES, deg);
    k_scan1<<<49, 1024, 0, stream>>>(deg, offs, bsums);   // offs used as 'part' scratch here
    k_scan2<<<1, 64, 0, stream>>>(bsums, 49);
    k_scan3<<<(N_NODES + 255) / 256, 256, 0, stream>>>(offs, bsums, deg, offs, cursor, keys);
    k_fill<<<8 * NCHUNKS, 256, 0, stream>>>(ei + N_EDGES, keyv, cursor, keys);

    for (int l = 0; l < 2; ++l) {
        k_agg<<<NPAD / 16, 256, 0, stream>>>(h_buf, offs, keys,
                                             e1 + l * 896, e2 + l * 384, aggb);
        k_mlp<<<MBLK, 256, 0, stream>>>((unsigned short*)aggb, w1t + l * 32768, b1 + l * 256,
                                        w2t + l * 32768, b2 + l * 128, partials);
        k_bnred<<<1, 256, 0, stream>>>(partials, gm + l * 128, bt + l * 128, ab);
        k_bnnorm<<<(N_NODES * 64) / 256, 256, 0, stream>>>(aggb, ab, h_buf, (float2*)d_out, l);
    }
}